// Round 11
// baseline (226.353 us; speedup 1.0000x reference)
//
#include <hip/hip_runtime.h>
#include <hip/hip_fp16.h>

#define IN_DIM 128
#define OUT_DIM 64
#define RPB 128          // rows per bucket (in-LDS sort+agg)
#define MAXB 800         // max buckets  (n_nodes <= 102400)
#define EPB 4096         // edges per block in fill part (512 thr x 8)
#define ENTL 2304        // LDS entry cap per bucket (mean 2048 + >5 sigma)
#define CAP 3584         // per-bucket entA region capacity (mean 3180 + 6 sigma)
#define NWH 320          // wh-part blocks (8 waves each = 2560 wave-slots)

typedef __attribute__((ext_vector_type(8))) _Float16 half8;
typedef __attribute__((ext_vector_type(4))) float f32x4;

// Tiny prologue: zero the per-bucket allocation cursors. Must be a separate
// launch (fill blocks may not assume any cross-block dispatch ordering).
__global__ __launch_bounds__(256) void k_zero(int* __restrict__ gcur) {
  for (int i = threadIdx.x; i < MAXB; i += 256) gcur[i] = 0;
}

// Fat kernel: blocks [0,nfill) = fill body, blocks [nfill,nfill+NWH) = wh
// body. The two are data-independent (fill: ei/edge_attr -> entA; wh:
// h/weights -> wh/s_row/s_col) and stress different pipes, so they
// co-schedule instead of serializing as two launches.
__global__ __launch_bounds__(512) void k_whfill(
    const float* __restrict__ h, const float* __restrict__ w_w,
    const float* __restrict__ w_b, const float* __restrict__ a_w,
    const int* __restrict__ ei, const float* __restrict__ edge_attr,
    __half* __restrict__ wh, float* __restrict__ s_row,
    float* __restrict__ s_col, int* __restrict__ gcur,
    int2* __restrict__ entA, int n_nodes, int nedges, int nb, int nfill) {
  if ((int)blockIdx.x < nfill) {
    // ---------------- fill body ----------------
    __shared__ int hist[MAXB];   // this block's per-bucket count
    __shared__ int cbase[MAXB];  // this block's chunk base (absolute)
    __shared__ int curs[MAXB];   // scatter cursor
    for (int b = threadIdx.x; b < MAXB; b += 512) hist[b] = 0;
    const float aw0 = a_w[128], aw1 = a_w[129], aw2 = a_w[130], aw3 = a_w[131];
    const float aw4 = a_w[132], aw5 = a_w[133], aw6 = a_w[134], aw7 = a_w[135];
    __syncthreads();
    const int e0 = blockIdx.x * EPB;
    int row[8], col[8];
    float s[8];
#pragma unroll
    for (int k = 0; k < 8; ++k) {
      int e = e0 + k * 512 + threadIdx.x;
      if (e < nedges) {
        row[k] = ei[e];
        col[k] = ei[nedges + e];
      } else {
        row[k] = -1;
        col[k] = 0;
      }
    }
#pragma unroll
    for (int k = 0; k < 8; ++k) {
      int e = e0 + k * 512 + threadIdx.x;
      if (row[k] >= 0) {
        const float4* ea = (const float4*)(edge_attr + (size_t)e * 8);
        float4 u = ea[0], v = ea[1];
        float t = u.x * aw0 + u.y * aw1 + u.z * aw2 + u.w * aw3;
        t += v.x * aw4 + v.y * aw5 + v.z * aw6 + v.w * aw7;
        s[k] = t;
      } else {
        s[k] = 0.f;
      }
    }
#pragma unroll
    for (int k = 0; k < 8; ++k)
      if (row[k] >= 0) atomicAdd(&hist[row[k] >> 7], 1);
    __syncthreads();
    for (int b = threadIdx.x; b < nb; b += 512) {
      int c = hist[b];
      int cb = 0;
      if (c > 0) cb = b * CAP + atomicAdd(&gcur[b], (c + 7) & ~7);
      cbase[b] = cb;
      curs[b] = cb;
    }
    __syncthreads();
#pragma unroll
    for (int k = 0; k < 8; ++k) {
      if (row[k] >= 0) {
        int bb = row[k] >> 7;
        int pos = atomicAdd(&curs[bb], 1);
        entA[pos] = make_int2(((row[k] & 127) << 17) | col[k],
                              __float_as_int(s[k]));
      }
    }
    __syncthreads();
    for (int b = threadIdx.x; b < nb; b += 512) {
      int c = hist[b];
      if (c > 0) {
        int st = cbase[b] + c, end = cbase[b] + ((c + 7) & ~7);
        for (int k = st; k < end; ++k) entA[k] = make_int2(-1, 0);
      }
    }
  } else {
    // ---------------- wh body (MFMA, 8 waves per block) ----------------
    __shared__ _Float16 wf[4 * 4 * 64 * 8];
    for (int idx = threadIdx.x; idx < IN_DIM * OUT_DIM; idx += 512) {
      int k = idx >> 6, c = idx & 63;            // w_w[k][c], coalesced read
      int mt = c >> 4;
      int kt = k >> 5;
      int l = (((k >> 3) & 3) << 4) | (c & 15);  // lane owning this (k,c)
      int j = k & 7;
      wf[(((mt << 2) | kt) << 9) | (l << 3) | j] = (_Float16)w_w[idx];
    }
    __syncthreads();

    const int lane = threadIdx.x & 63;
    const int wv = threadIdx.x >> 6;            // 0..7

    half8 A[4][4];
#pragma unroll
    for (int mt = 0; mt < 4; ++mt)
#pragma unroll
      for (int kt = 0; kt < 4; ++kt)
        A[mt][kt] =
            *(const half8*)&wf[(((mt << 2) | kt) << 9) | (lane << 3)];

    const int cbase2 = (lane >> 4) << 2;
    f32x4 bq[4], a1q[4], a2q[4];
#pragma unroll
    for (int mt = 0; mt < 4; ++mt) {
      bq[mt] = *(const f32x4*)&w_b[mt * 16 + cbase2];
      a1q[mt] = *(const f32x4*)&a_w[mt * 16 + cbase2];
      a2q[mt] = *(const f32x4*)&a_w[OUT_DIM + mt * 16 + cbase2];
    }

    const int wb = blockIdx.x - nfill;
    const int ntiles = (n_nodes + 15) >> 4;
    const int tstride = NWH * 8;
    for (int t = wb * 8 + wv; t < ntiles; t += tstride) {
      const int n0 = t << 4;
      const int node = n0 + (lane & 15);
      const int nodec = node < n_nodes ? node : n_nodes - 1;
      const float4* hv =
          (const float4*)(h + (size_t)nodec * IN_DIM + ((lane >> 4) << 3));
      float4 p[8];
#pragma unroll
      for (int kt = 0; kt < 4; ++kt) {
        p[2 * kt] = hv[kt * 8];
        p[2 * kt + 1] = hv[kt * 8 + 1];
      }
      f32x4 C[4];
#pragma unroll
      for (int mt = 0; mt < 4; ++mt) C[mt] = (f32x4){0.f, 0.f, 0.f, 0.f};
#pragma unroll
      for (int kt = 0; kt < 4; ++kt) {
        const float4 u = p[2 * kt], v = p[2 * kt + 1];
        half8 B;
        B[0] = (_Float16)u.x; B[1] = (_Float16)u.y;
        B[2] = (_Float16)u.z; B[3] = (_Float16)u.w;
        B[4] = (_Float16)v.x; B[5] = (_Float16)v.y;
        B[6] = (_Float16)v.z; B[7] = (_Float16)v.w;
#pragma unroll
        for (int mt = 0; mt < 4; ++mt)
          C[mt] = __builtin_amdgcn_mfma_f32_16x16x32_f16(A[mt][kt], B, C[mt],
                                                         0, 0, 0);
      }
      float sr = 0.f, sc = 0.f;
      uint2 q[4];
#pragma unroll
      for (int mt = 0; mt < 4; ++mt) {
        f32x4 d = C[mt] + bq[mt];
        sr += d[0] * a1q[mt][0] + d[1] * a1q[mt][1] + d[2] * a1q[mt][2] +
              d[3] * a1q[mt][3];
        sc += d[0] * a2q[mt][0] + d[1] * a2q[mt][1] + d[2] * a2q[mt][2] +
              d[3] * a2q[mt][3];
        __half2 lo = __floats2half2_rn(d[0], d[1]);
        __half2 hi = __floats2half2_rn(d[2], d[3]);
        q[mt].x = *(unsigned int*)&lo;
        q[mt].y = *(unsigned int*)&hi;
      }
      if (node < n_nodes) {
        uint2* wrow = (uint2*)(wh + (size_t)node * OUT_DIM + cbase2);
        wrow[0] = q[0];
        wrow[4] = q[1];
        wrow[8] = q[2];
        wrow[12] = q[3];
      }
      sr += __shfl_xor(sr, 16, 64);
      sr += __shfl_xor(sr, 32, 64);
      sc += __shfl_xor(sc, 16, 64);
      sc += __shfl_xor(sc, 32, 64);
      if (lane < 16 && node < n_nodes) {
        s_row[node] = sr;
        s_col[node] = sc;
      }
    }
  }
}

// Phase 3 (fused sort+agg): one block per 128-row bucket. Stage bucket
// entries in registers, LDS-histogram rows, scan -> per-row starts,
// scatter row-sorted into LDS, then pull-agg.
// Agg processes TWO nodes per wave iteration: 4 gathers in flight for ALL
// nodes (incl. the deg<=16 majority, where R10's 4-deep never engaged) and
// the two independent reduce chains overlap.
__global__ __launch_bounds__(512) void k_sagg(
    const int2* __restrict__ entA, const int* __restrict__ gcur,
    const __half* __restrict__ wh,
    const float* __restrict__ s_row, const float* __restrict__ s_col,
    const float* __restrict__ a_b, float* __restrict__ out, int n_nodes) {
  __shared__ int2 entl[ENTL];
  __shared__ int hist[RPB], sd[RPB], starts[RPB], curs[RPB], degs[RPB];
  const int b = blockIdx.x;
  const int row0 = b << 7;
  const int t = threadIdx.x;
  if (t < RPB) hist[t] = 0;
  __syncthreads();
  const int c = gcur[b];       // padded count (sentinels included)
  const int base = b * CAP;
  // --- stage + histogram ---
  int2 e[8];
#pragma unroll
  for (int k = 0; k < 8; ++k) {
    int i = t + k * 512;
    e[k] = (i < c) ? entA[base + i] : make_int2(-1, 0);
  }
#pragma unroll
  for (int k = 0; k < 8; ++k)
    if (e[k].x >= 0) atomicAdd(&hist[e[k].x >> 17], 1);
  for (int i = t + 4096; i < c; i += 512) {  // overflow guard (never runs)
    int2 p = entA[base + i];
    if (p.x >= 0) atomicAdd(&hist[p.x >> 17], 1);
  }
  __syncthreads();
  // --- scan hist[128] ---
  int hh = 0;
  if (t < RPB) { hh = hist[t]; sd[t] = hh; }
  __syncthreads();
  for (int off = 1; off < RPB; off <<= 1) {
    int x = (t >= off && t < RPB) ? sd[t - off] : 0;
    __syncthreads();
    if (t < RPB) sd[t] += x;
    __syncthreads();
  }
  if (t < RPB) {
    int excl = sd[t] - hh;
    starts[t] = excl;
    curs[t] = excl;
    degs[t] = hh;
  }
  __syncthreads();
  // --- scatter row-sorted into LDS ---
#pragma unroll
  for (int k = 0; k < 8; ++k)
    if (e[k].x >= 0) {
      int p = atomicAdd(&curs[e[k].x >> 17], 1);
      if (p < ENTL) entl[p] = e[k];
    }
  for (int i = t + 4096; i < c; i += 512) {  // overflow guard (never runs)
    int2 p2 = entA[base + i];
    if (p2.x >= 0) {
      int p = atomicAdd(&curs[p2.x >> 17], 1);
      if (p < ENTL) entl[p] = p2;
    }
  }
  __syncthreads();
  // --- aggregate: 8 waves x 16 nodes each, TWO nodes per iteration ---
  const int wv = t >> 6;
  const int lane = t & 63;
  const int slot = lane >> 3, sub = lane & 7;
  const float ab = a_b[0];
  const uint4* whq = (const uint4*)wh;
  for (int j = 0; j < 16; j += 2) {
    const int rlA = wv * 16 + j, rlB = rlA + 1;
    const int nodeA = row0 + rlA, nodeB = row0 + rlB;
    const bool vA = nodeA < n_nodes;
    if (!vA) break;
    const bool vB = nodeB < n_nodes;
    const int stA = starts[rlA], dgA = degs[rlA];
    const int stB = starts[rlB], dgB = vB ? degs[rlB] : 0;
    const float sabA = s_row[nodeA] + ab;
    const float sabB = vB ? s_row[nodeB] + ab : 0.f;
    float accA[8] = {0.f, 0.f, 0.f, 0.f, 0.f, 0.f, 0.f, 0.f};
    float accB[8] = {0.f, 0.f, 0.f, 0.f, 0.f, 0.f, 0.f, 0.f};
    float lA = 0.f, lB = 0.f;
    const int dgmax = (dgB > dgA) ? dgB : dgA;
    for (int bas = 0; bas < dgmax; bas += 16) {
      const int iA0 = bas + slot, iA1 = iA0 + 8;
      const int iB0 = bas + slot, iB1 = iB0 + 8;
      const bool gA0 = iA0 < dgA, gA1 = iA1 < dgA;
      const bool gB0 = iB0 < dgB, gB1 = iB1 < dgB;
      int2 pA0 = gA0 ? entl[stA + iA0] : make_int2(0, 0);
      int2 pA1 = gA1 ? entl[stA + iA1] : make_int2(0, 0);
      int2 pB0 = gB0 ? entl[stB + iB0] : make_int2(0, 0);
      int2 pB1 = gB1 ? entl[stB + iB1] : make_int2(0, 0);
      const int cA0 = pA0.x & 0x1FFFF, cA1 = pA1.x & 0x1FFFF;
      const int cB0 = pB0.x & 0x1FFFF, cB1 = pB1.x & 0x1FFFF;
      uint4 qA0 = make_uint4(0, 0, 0, 0), qA1 = make_uint4(0, 0, 0, 0);
      uint4 qB0 = make_uint4(0, 0, 0, 0), qB1 = make_uint4(0, 0, 0, 0);
      float scA0 = 0.f, scA1 = 0.f, scB0 = 0.f, scB1 = 0.f;
      if (gA0) { qA0 = whq[(size_t)cA0 * 8 + sub]; scA0 = s_col[cA0]; }
      if (gA1) { qA1 = whq[(size_t)cA1 * 8 + sub]; scA1 = s_col[cA1]; }
      if (gB0) { qB0 = whq[(size_t)cB0 * 8 + sub]; scB0 = s_col[cB0]; }
      if (gB1) { qB1 = whq[(size_t)cB1 * 8 + sub]; scB1 = s_col[cB1]; }
      if (gA0) {
        float s = sabA + scA0 + __int_as_float(pA0.y);
        float ev = (s > 0.f) ? s : 0.01f * s;  // leaky_relu
        float a = __expf(ev);  // softmax shift-invariance: no segment max
        float2 f0 = __half22float2(*(__half2*)&qA0.x);
        float2 f1 = __half22float2(*(__half2*)&qA0.y);
        float2 f2 = __half22float2(*(__half2*)&qA0.z);
        float2 f3 = __half22float2(*(__half2*)&qA0.w);
        accA[0] = fmaf(a, f0.x, accA[0]); accA[1] = fmaf(a, f0.y, accA[1]);
        accA[2] = fmaf(a, f1.x, accA[2]); accA[3] = fmaf(a, f1.y, accA[3]);
        accA[4] = fmaf(a, f2.x, accA[4]); accA[5] = fmaf(a, f2.y, accA[5]);
        accA[6] = fmaf(a, f3.x, accA[6]); accA[7] = fmaf(a, f3.y, accA[7]);
        if (sub == 0) lA += a;
      }
      if (gA1) {
        float s = sabA + scA1 + __int_as_float(pA1.y);
        float ev = (s > 0.f) ? s : 0.01f * s;
        float a = __expf(ev);
        float2 f0 = __half22float2(*(__half2*)&qA1.x);
        float2 f1 = __half22float2(*(__half2*)&qA1.y);
        float2 f2 = __half22float2(*(__half2*)&qA1.z);
        float2 f3 = __half22float2(*(__half2*)&qA1.w);
        accA[0] = fmaf(a, f0.x, accA[0]); accA[1] = fmaf(a, f0.y, accA[1]);
        accA[2] = fmaf(a, f1.x, accA[2]); accA[3] = fmaf(a, f1.y, accA[3]);
        accA[4] = fmaf(a, f2.x, accA[4]); accA[5] = fmaf(a, f2.y, accA[5]);
        accA[6] = fmaf(a, f3.x, accA[6]); accA[7] = fmaf(a, f3.y, accA[7]);
        if (sub == 0) lA += a;
      }
      if (gB0) {
        float s = sabB + scB0 + __int_as_float(pB0.y);
        float ev = (s > 0.f) ? s : 0.01f * s;
        float a = __expf(ev);
        float2 f0 = __half22float2(*(__half2*)&qB0.x);
        float2 f1 = __half22float2(*(__half2*)&qB0.y);
        float2 f2 = __half22float2(*(__half2*)&qB0.z);
        float2 f3 = __half22float2(*(__half2*)&qB0.w);
        accB[0] = fmaf(a, f0.x, accB[0]); accB[1] = fmaf(a, f0.y, accB[1]);
        accB[2] = fmaf(a, f1.x, accB[2]); accB[3] = fmaf(a, f1.y, accB[3]);
        accB[4] = fmaf(a, f2.x, accB[4]); accB[5] = fmaf(a, f2.y, accB[5]);
        accB[6] = fmaf(a, f3.x, accB[6]); accB[7] = fmaf(a, f3.y, accB[7]);
        if (sub == 0) lB += a;
      }
      if (gB1) {
        float s = sabB + scB1 + __int_as_float(pB1.y);
        float ev = (s > 0.f) ? s : 0.01f * s;
        float a = __expf(ev);
        float2 f0 = __half22float2(*(__half2*)&qB1.x);
        float2 f1 = __half22float2(*(__half2*)&qB1.y);
        float2 f2 = __half22float2(*(__half2*)&qB1.z);
        float2 f3 = __half22float2(*(__half2*)&qB1.w);
        accB[0] = fmaf(a, f0.x, accB[0]); accB[1] = fmaf(a, f0.y, accB[1]);
        accB[2] = fmaf(a, f1.x, accB[2]); accB[3] = fmaf(a, f1.y, accB[3]);
        accB[4] = fmaf(a, f2.x, accB[4]); accB[5] = fmaf(a, f2.y, accB[5]);
        accB[6] = fmaf(a, f3.x, accB[6]); accB[7] = fmaf(a, f3.y, accB[7]);
        if (sub == 0) lB += a;
      }
    }
    // two independent reduce chains, interleaved for ILP
#pragma unroll
    for (int d = 0; d < 8; ++d) {
      accA[d] += __shfl_xor(accA[d], 8, 64);
      accB[d] += __shfl_xor(accB[d], 8, 64);
      accA[d] += __shfl_xor(accA[d], 16, 64);
      accB[d] += __shfl_xor(accB[d], 16, 64);
      accA[d] += __shfl_xor(accA[d], 32, 64);
      accB[d] += __shfl_xor(accB[d], 32, 64);
    }
    lA += __shfl_xor(lA, 8, 64);
    lB += __shfl_xor(lB, 8, 64);
    lA += __shfl_xor(lA, 16, 64);
    lB += __shfl_xor(lB, 16, 64);
    lA += __shfl_xor(lA, 32, 64);
    lB += __shfl_xor(lB, 32, 64);
    float ltA = __shfl(lA, 0, 64);
    float ltB = __shfl(lB, 0, 64);
    if (slot == 0) {
      float invA = 1.0f / (ltA + 1e-8f);
      float4 oA0 = make_float4(accA[0] * invA, accA[1] * invA,
                               accA[2] * invA, accA[3] * invA);
      float4 oA1 = make_float4(accA[4] * invA, accA[5] * invA,
                               accA[6] * invA, accA[7] * invA);
      float4* orowA = (float4*)out + (size_t)nodeA * 16 + sub * 2;
      orowA[0] = oA0;
      orowA[1] = oA1;
      if (vB) {
        float invB = 1.0f / (ltB + 1e-8f);
        float4 oB0 = make_float4(accB[0] * invB, accB[1] * invB,
                                 accB[2] * invB, accB[3] * invB);
        float4 oB1 = make_float4(accB[4] * invB, accB[5] * invB,
                                 accB[6] * invB, accB[7] * invB);
        float4* orowB = (float4*)out + (size_t)nodeB * 16 + sub * 2;
        orowB[0] = oB0;
        orowB[1] = oB1;
      }
    }
  }
}

extern "C" void kernel_launch(void* const* d_in, const int* in_sizes, int n_in,
                              void* d_out, int out_size, void* d_ws, size_t ws_size,
                              hipStream_t stream) {
  const float* h         = (const float*)d_in[0];
  const int*   ei        = (const int*)d_in[1];
  const float* edge_attr = (const float*)d_in[2];
  const float* w_w       = (const float*)d_in[3];
  const float* w_b       = (const float*)d_in[4];
  const float* a_w       = (const float*)d_in[5];
  const float* a_b       = (const float*)d_in[6];
  const int n_nodes = in_sizes[0] / IN_DIM;
  const int nedges  = in_sizes[1] / 2;
  const int nb   = (n_nodes + RPB - 1) / RPB;   // 782
  const int nebl = (nedges + EPB - 1) / EPB;    // 391

  // Workspace (~36 MB): wh | entA (nb*CAP) | gcur | s_row | s_col
  __half* wh       = (__half*)d_ws;                           // n*64 fp16
  int2*  entA      = (int2*)(wh + (size_t)n_nodes * OUT_DIM); // nb*CAP
  int*   gcur      = (int*)(entA + (size_t)nb * CAP);         // MAXB
  float* s_row     = (float*)(gcur + MAXB);                   // n
  float* s_col     = s_row + n_nodes;                         // n

  k_zero<<<1, 256, 0, stream>>>(gcur);
  k_whfill<<<nebl + NWH, 512, 0, stream>>>(h, w_w, w_b, a_w, ei, edge_attr,
                                           wh, s_row, s_col, gcur, entA,
                                           n_nodes, nedges, nb, nebl);
  k_sagg<<<nb, 512, 0, stream>>>(entA, gcur, wh, s_row, s_col, a_b,
                                 (float*)d_out, n_nodes);
}